// Round 6
// baseline (546.196 us; speedup 1.0000x reference)
//
#include <hip/hip_runtime.h>
#include <math.h>

#define N_NODES 50000
#define N_ROWS_PAD 50048   // 782 * 64
#define N_GRAPHS 500
#define NPG 100
#define N_EDGES 500000
#define F_IN 16
#define HID 64
#define EW_CAP 1792        // max intra-graph edges (mean 1000, sigma ~32)

#define SELU_SCALE 1.0507009873554804934193349852946f
#define SELU_ALPHA 1.6732632423543772848170429916717f

typedef __attribute__((ext_vector_type(8))) short short8;
typedef __attribute__((ext_vector_type(4))) float floatx4;

__device__ __forceinline__ float lrelu(float x){ return x > 0.f ? x : 0.2f * x; }
__device__ __forceinline__ float eluf(float x){ return x > 0.f ? x : expf(x) - 1.f; }
__device__ __forceinline__ float seluf(float x){
    return x > 0.f ? SELU_SCALE * x : SELU_SCALE * (SELU_ALPHA * (expf(x) - 1.f));
}
__device__ __forceinline__ unsigned short f2bf(float x){
    unsigned u = __float_as_uint(x);
    return (unsigned short)((u + 0x7FFFu + ((u >> 16) & 1u)) >> 16);
}

// ---------------- CSR build ----------------
__global__ void k_count(const int* __restrict__ dst, int* __restrict__ counts){
    int e = blockIdx.x * 256 + threadIdx.x;
    if (e < N_EDGES) atomicAdd(&counts[dst[e]], 1);
}

__global__ void k_local_scan(const int* __restrict__ counts, int* __restrict__ local_off,
                             int* __restrict__ graph_tot){
    __shared__ int s[128];
    int g = blockIdx.x, t = threadIdx.x;
    int v = (t < NPG) ? counts[g * NPG + t] : 0;
    s[t] = v; __syncthreads();
    for (int o = 1; o < 128; o <<= 1){
        int x = (t >= o) ? s[t - o] : 0;
        __syncthreads();
        s[t] += x;
        __syncthreads();
    }
    if (t < NPG) local_off[g * NPG + t] = s[t] - v;   // exclusive
    if (t == 127) graph_tot[g] = s[127];
}

__global__ void k_graph_scan(const int* __restrict__ graph_tot, int* __restrict__ graph_base){
    __shared__ int s[512];
    int t = threadIdx.x;
    int v = (t < N_GRAPHS) ? graph_tot[t] : 0;
    s[t] = v; __syncthreads();
    for (int o = 1; o < 512; o <<= 1){
        int x = (t >= o) ? s[t - o] : 0;
        __syncthreads();
        s[t] += x;
        __syncthreads();
    }
    if (t < N_GRAPHS) graph_base[t] = s[t] - v;       // exclusive
}

__global__ void k_off(const int* __restrict__ local_off, const int* __restrict__ graph_base,
                      int* __restrict__ node_off, int* __restrict__ write_ptr){
    int n = blockIdx.x * 256 + threadIdx.x;
    if (n < N_NODES){
        int v = local_off[n] + graph_base[n / NPG];
        node_off[n] = v;
        write_ptr[n] = v;
    }
}

__global__ void k_scatter(const int* __restrict__ src, const int* __restrict__ dst,
                          int* __restrict__ write_ptr, int* __restrict__ csr){
    int e = blockIdx.x * 256 + threadIdx.x;
    if (e < N_EDGES){
        int d = dst[e];
        int pos = atomicAdd(&write_ptr[d], 1);
        csr[pos] = src[e];
    }
}

// ---------------- GraphNorm ----------------
__global__ void k_gnorm(const float* __restrict__ x, const float* __restrict__ w,
                        const float* __restrict__ b, const float* __restrict__ ms,
                        float* __restrict__ y){
    __shared__ float sx[NPG * F_IN];
    __shared__ float red[16][16];
    __shared__ float meanS[16], varS[16];
    int g = blockIdx.x, t = threadIdx.x;
    for (int idx = t; idx < NPG * F_IN; idx += 256) sx[idx] = x[g * NPG * F_IN + idx];
    __syncthreads();
    int f = t & 15, grp = t >> 4;
    float p = 0.f;
    for (int i = grp; i < NPG; i += 16) p += sx[i * 16 + f];
    red[grp][f] = p; __syncthreads();
    if (t < 16){
        float s = 0.f;
        for (int i = 0; i < 16; i++) s += red[i][t];
        meanS[t] = s * (1.f / 100.f);
    }
    __syncthreads();
    float mm = meanS[f] * ms[f];
    p = 0.f;
    for (int i = grp; i < NPG; i += 16){ float v = sx[i * 16 + f] - mm; p += v * v; }
    red[grp][f] = p; __syncthreads();
    if (t < 16){
        float s = 0.f;
        for (int i = 0; i < 16; i++) s += red[i][t];
        varS[t] = s * (1.f / 100.f);
    }
    __syncthreads();
    for (int idx = t; idx < NPG * F_IN; idx += 256){
        int ff = idx & 15;
        float v = sx[idx] - meanS[ff] * ms[ff];
        y[g * NPG * F_IN + idx] = w[ff] * v * rsqrtf(varS[ff] + 1e-5f) + b[ff];
    }
}

// ---------------- fp32 tiled GEMM (conv1 only, K=16) ----------------
__global__ void k_gemm_tiled(const float* __restrict__ X, const float* __restrict__ W,
                             float* __restrict__ Y, int N, int K, int OUT){
    __shared__ float As[16][68];
    __shared__ float Bs[16][68];
    int t = threadIdx.x;
    int r0 = blockIdx.y * 64;
    int c0 = blockIdx.x * 64;
    int tx = t & 15, ty = t >> 4;
    float acc[4][4];
    #pragma unroll
    for (int i = 0; i < 4; i++)
        #pragma unroll
        for (int j = 0; j < 4; j++) acc[i][j] = 0.f;

    int lk = t & 15;
    int lm0 = t >> 4;
    int ln = t & 63;
    int lkb = t >> 6;

    for (int kt = 0; kt < K; kt += 16){
        #pragma unroll
        for (int i = 0; i < 4; i++){
            int m = lm0 + i * 16;
            int row = r0 + m;
            As[lk][m] = (row < N) ? X[row * K + kt + lk] : 0.f;
        }
        #pragma unroll
        for (int i = 0; i < 4; i++){
            int k = lkb + i * 4;
            Bs[k][ln] = W[(kt + k) * OUT + c0 + ln];
        }
        __syncthreads();
        #pragma unroll
        for (int k = 0; k < 16; k++){
            float4 a = *(const float4*)&As[k][ty * 4];
            float4 b = *(const float4*)&Bs[k][tx * 4];
            float av[4] = {a.x, a.y, a.z, a.w};
            float bv[4] = {b.x, b.y, b.z, b.w};
            #pragma unroll
            for (int i = 0; i < 4; i++)
                #pragma unroll
                for (int j = 0; j < 4; j++) acc[i][j] += av[i] * bv[j];
        }
        __syncthreads();
    }
    #pragma unroll
    for (int i = 0; i < 4; i++){
        int row = r0 + ty * 4 + i;
        if (row < N){
            float4 v = make_float4(acc[i][0], acc[i][1], acc[i][2], acc[i][3]);
            *(float4*)&Y[row * OUT + c0 + tx * 4] = v;
        }
    }
}

// ---------------- W pack to MFMA-B-fragment order + bf16 ----------------
__global__ void k_pack_w(const float* __restrict__ W, unsigned short* __restrict__ Wp,
                         int K, int OUT){
    int idx = blockIdx.x * 256 + threadIdx.x;
    if (idx >= K * OUT) return;
    int k = idx / OUT, n = idx - k * OUT;
    Wp[(((k >> 3) * OUT) + n) * 8 + (k & 7)] = f2bf(W[idx]);
}

// ---------------- bf16 MFMA GEMM ----------------
__global__ void k_gemm_mfma(const unsigned short* __restrict__ Xb,
                            const unsigned short* __restrict__ Wp,
                            float* __restrict__ Y, int N, int K, int OUT){
    int t = threadIdx.x;
    int wave = t >> 6, lane = t & 63;
    int quad = lane >> 4, ln = lane & 15;
    int r0 = blockIdx.y * 64 + wave * 16;
    int c0 = blockIdx.x * 64;

    floatx4 acc[4];
    #pragma unroll
    for (int f = 0; f < 4; f++) acc[f] = (floatx4){0.f, 0.f, 0.f, 0.f};

    const unsigned short* aptr = Xb + (size_t)(r0 + ln) * K + quad * 8;
    for (int kt = 0; kt < K; kt += 32){
        short8 a = *(const short8*)(aptr + kt);
        int kc = (kt >> 3) + quad;
        #pragma unroll
        for (int f = 0; f < 4; f++){
            short8 b = *(const short8*)(Wp + ((size_t)kc * OUT + c0 + f * 16 + ln) * 8);
            acc[f] = __builtin_amdgcn_mfma_f32_16x16x32_bf16(a, b, acc[f], 0, 0, 0);
        }
    }
    int rowb = r0 + quad * 4;
    #pragma unroll
    for (int f = 0; f < 4; f++){
        int col = c0 + f * 16 + ln;
        #pragma unroll
        for (int rg = 0; rg < 4; rg++){
            int row = rowb + rg;
            if (row < N) Y[(size_t)row * OUT + col] = acc[f][rg];
        }
    }
}

// ---------------- fused GAT layer, one block per (graph, head) ----------------
// H=4 heads split across blocks: grid = 500*4. 256 thr = 4 waves.
// LDS ~35 KB -> 4 blocks/CU. h fp32 in, bf16 out, ELU applied.
__global__ void __launch_bounds__(256)
k_fused4h(const float* __restrict__ h, const float* __restrict__ as,
          const float* __restrict__ ad, const float* __restrict__ bias,
          const int* __restrict__ csr, const int* __restrict__ noff,
          const int* __restrict__ cnt, unsigned short* __restrict__ out_bf){
    __shared__ __align__(16) float hl[NPG * 64];      // 25600 B (this head's slice)
    __shared__ int   csl[EW_CAP];                     // 7168 B
    __shared__ float asrcl[NPG], adstl[NPG];
    __shared__ float asl[64], adl[64];
    __shared__ int offl[NPG], cntl[NPG];

    int bid = blockIdx.x;
    int g = bid >> 2, hh = bid & 3;
    int t = threadIdx.x, wave = t >> 6, lane = t & 63;
    int base = g * NPG;

    // phase 0: stage h-slice (100 rows x 64 cols), att vectors, offsets
    for (int i = t; i < NPG * 16; i += 256){
        int row = i >> 4, c4 = i & 15;
        ((float4*)hl)[i] = *(const float4*)(h + (size_t)(base + row) * 256 + hh * 64 + c4 * 4);
    }
    if (t < 64){ asl[t] = as[hh * 64 + t]; adl[t] = ad[hh * 64 + t]; }
    if (t < NPG){ offl[t] = noff[base + t]; cntl[t] = cnt[base + t]; }
    __syncthreads();

    // phase 1: stage CSR slice (localized ids) + logits (one wave per node)
    int ebeg = offl[0];
    int etot = offl[NPG - 1] + cntl[NPG - 1] - ebeg;
    int eln = etot < EW_CAP ? etot : EW_CAP;
    for (int i = t; i < eln; i += 256) csl[i] = csr[ebeg + i] - base;

    for (int n = wave; n < NPG; n += 4){
        float v = hl[n * 64 + lane];
        float ps = v * asl[lane];
        float pd = v * adl[lane];
        #pragma unroll
        for (int o = 32; o >= 1; o >>= 1){
            ps += __shfl_xor(ps, o);
            pd += __shfl_xor(pd, o);
        }
        if (lane == 0){ asrcl[n] = ps; adstl[n] = pd; }
    }
    __syncthreads();

    // phase 2: per dst node (one wave each): softmax (lane=edge) + aggregate (lane=channel)
    float bl = bias[hh * 64 + lane];
    for (int d = wave; d < NPG; d += 4){
        float adv = adstl[d];
        float es = lrelu(asrcl[d] + adv);
        int ebg = offl[d] - ebeg;
        int n   = cntl[d];
        // lane=edge: load idx + logit once
        int   s0 = (lane < n) ? csl[ebg + lane] : 0;
        float v0 = (lane < n) ? lrelu(asrcl[s0] + adv) : -1e30f;
        int   s1 = 0; float v1 = -1e30f;
        if (n > 64){                       // essentially never (deg ~Poisson(10))
            int j = 64 + lane;
            if (j < n){ s1 = csl[ebg + j]; v1 = lrelu(asrcl[s1] + adv); }
        }
        float m = fmaxf(es, fmaxf(v0, v1));
        #pragma unroll
        for (int o = 32; o >= 1; o >>= 1) m = fmaxf(m, __shfl_xor(m, o));
        float w0 = (lane < n) ? expf(v0 - m) : 0.f;
        float w1 = (n > 64 && 64 + lane < n) ? expf(v1 - m) : 0.f;
        float p = w0 + w1;
        #pragma unroll
        for (int o = 32; o >= 1; o >>= 1) p += __shfl_xor(p, o);
        float wsf = expf(es - m);
        float rs = 1.f / (p + wsf);
        // lane=channel aggregation; edge (idx,w) broadcast from registers via shfl
        float acc = wsf * hl[d * 64 + lane];
        int nn = n < 64 ? n : 64;
        int j = 0;
        for (; j + 4 <= nn; j += 4){
            int   a0 = __shfl(s0, j),     a1 = __shfl(s0, j + 1);
            int   a2 = __shfl(s0, j + 2), a3 = __shfl(s0, j + 3);
            float u0 = __shfl(w0, j),     u1 = __shfl(w0, j + 1);
            float u2 = __shfl(w0, j + 2), u3 = __shfl(w0, j + 3);
            acc = fmaf(u0, hl[a0 * 64 + lane], acc);
            acc = fmaf(u1, hl[a1 * 64 + lane], acc);
            acc = fmaf(u2, hl[a2 * 64 + lane], acc);
            acc = fmaf(u3, hl[a3 * 64 + lane], acc);
        }
        for (; j < nn; j++){
            int   a = __shfl(s0, j);
            float u = __shfl(w0, j);
            acc = fmaf(u, hl[a * 64 + lane], acc);
        }
        if (n > 64){
            int n2 = n - 64; if (n2 > 64) n2 = 64;
            for (int jj = 0; jj < n2; jj++){
                int   a = __shfl(s1, jj);
                float u = __shfl(w1, jj);
                acc = fmaf(u, hl[a * 64 + lane], acc);
            }
        }
        out_bf[(size_t)(base + d) * 256 + hh * 64 + lane] = f2bf(eluf(acc * rs + bl));
    }
}

// H=1, C=64, one block per graph, fp32 out, no ELU (conv3 -> head).
__global__ void __launch_bounds__(256)
k_fused1(const float* __restrict__ h, const float* __restrict__ as,
         const float* __restrict__ ad, const float* __restrict__ bias,
         const int* __restrict__ csr, const int* __restrict__ noff,
         const int* __restrict__ cnt, float* __restrict__ out){
    __shared__ __align__(16) float hl[NPG * 64];
    __shared__ int   csl[EW_CAP];
    __shared__ float asrcl[NPG], adstl[NPG];
    __shared__ float asl[64], adl[64];
    __shared__ int offl[NPG], cntl[NPG];

    int g = blockIdx.x, t = threadIdx.x;
    int wave = t >> 6, lane = t & 63;
    int base = g * NPG;

    const float4* hsrc = (const float4*)(h + (size_t)base * 64);
    for (int i = t; i < NPG * 16; i += 256) ((float4*)hl)[i] = hsrc[i];
    if (t < 64){ asl[t] = as[t]; adl[t] = ad[t]; }
    if (t < NPG){ offl[t] = noff[base + t]; cntl[t] = cnt[base + t]; }
    __syncthreads();

    int ebeg = offl[0];
    int etot = offl[NPG - 1] + cntl[NPG - 1] - ebeg;
    int eln = etot < EW_CAP ? etot : EW_CAP;
    for (int i = t; i < eln; i += 256) csl[i] = csr[ebeg + i] - base;

    for (int n = wave; n < NPG; n += 4){
        float v = hl[n * 64 + lane];
        float ps = v * asl[lane];
        float pd = v * adl[lane];
        #pragma unroll
        for (int o = 32; o >= 1; o >>= 1){
            ps += __shfl_xor(ps, o);
            pd += __shfl_xor(pd, o);
        }
        if (lane == 0){ asrcl[n] = ps; adstl[n] = pd; }
    }
    __syncthreads();

    float bl = bias[lane];
    for (int d = wave; d < NPG; d += 4){
        float adv = adstl[d];
        float es = lrelu(asrcl[d] + adv);
        int ebg = offl[d] - ebeg;
        int n   = cntl[d];
        int   s0 = (lane < n) ? csl[ebg + lane] : 0;
        float v0 = (lane < n) ? lrelu(asrcl[s0] + adv) : -1e30f;
        int   s1 = 0; float v1 = -1e30f;
        if (n > 64){
            int j = 64 + lane;
            if (j < n){ s1 = csl[ebg + j]; v1 = lrelu(asrcl[s1] + adv); }
        }
        float m = fmaxf(es, fmaxf(v0, v1));
        #pragma unroll
        for (int o = 32; o >= 1; o >>= 1) m = fmaxf(m, __shfl_xor(m, o));
        float w0 = (lane < n) ? expf(v0 - m) : 0.f;
        float w1 = (n > 64 && 64 + lane < n) ? expf(v1 - m) : 0.f;
        float p = w0 + w1;
        #pragma unroll
        for (int o = 32; o >= 1; o >>= 1) p += __shfl_xor(p, o);
        float wsf = expf(es - m);
        float rs = 1.f / (p + wsf);
        float acc = wsf * hl[d * 64 + lane];
        int nn = n < 64 ? n : 64;
        int j = 0;
        for (; j + 4 <= nn; j += 4){
            int   a0 = __shfl(s0, j),     a1 = __shfl(s0, j + 1);
            int   a2 = __shfl(s0, j + 2), a3 = __shfl(s0, j + 3);
            float u0 = __shfl(w0, j),     u1 = __shfl(w0, j + 1);
            float u2 = __shfl(w0, j + 2), u3 = __shfl(w0, j + 3);
            acc = fmaf(u0, hl[a0 * 64 + lane], acc);
            acc = fmaf(u1, hl[a1 * 64 + lane], acc);
            acc = fmaf(u2, hl[a2 * 64 + lane], acc);
            acc = fmaf(u3, hl[a3 * 64 + lane], acc);
        }
        for (; j < nn; j++){
            int   a = __shfl(s0, j);
            float u = __shfl(w0, j);
            acc = fmaf(u, hl[a * 64 + lane], acc);
        }
        if (n > 64){
            int n2 = n - 64; if (n2 > 64) n2 = 64;
            for (int jj = 0; jj < n2; jj++){
                int   a = __shfl(s1, jj);
                float u = __shfl(w1, jj);
                acc = fmaf(u, hl[a * 64 + lane], acc);
            }
        }
        out[(size_t)(base + d) * 64 + lane] = acc * rs + bl;
    }
}

// ---------------- pooling + BN + dense head ----------------
__global__ void k_head(const float* __restrict__ x3, const float* __restrict__ gin,
                       const float* __restrict__ bn_g, const float* __restrict__ bn_b,
                       const float* __restrict__ bn_m, const float* __restrict__ bn_v,
                       const float* __restrict__ Wd1, const float* __restrict__ bd1,
                       const float* __restrict__ Wd2, const float* __restrict__ bd2,
                       const float* __restrict__ Wo, const float* __restrict__ bo,
                       float* __restrict__ out){
    __shared__ float red[256];
    __shared__ float gv[68];
    __shared__ float g2[64];
    __shared__ float g3[64];
    int g = blockIdx.x, t = threadIdx.x;
    int c = t & 63, grp = t >> 6;
    float p = 0.f;
    for (int i = grp; i < NPG; i += 4) p += x3[(g * NPG + i) * 64 + c];
    red[t] = p; __syncthreads();
    if (t < 64){
        float s = red[t] + red[t + 64] + red[t + 128] + red[t + 192];
        float mean = s * (1.f / 100.f);
        gv[t] = (mean - bn_m[t]) * rsqrtf(bn_v[t] + 1e-5f) * bn_g[t] + bn_b[t];
    } else if (t < 68){
        int j = t - 64;
        float v = gin[g * 4 + j];
        gv[t] = (v - bn_m[t]) * rsqrtf(bn_v[t] + 1e-5f) * bn_g[t] + bn_b[t];
    }
    __syncthreads();
    if (t < 64){
        float s = bd1[t];
        for (int i = 0; i < 68; i++) s += gv[i] * Wd1[i * 64 + t];
        g2[t] = seluf(s);
    }
    __syncthreads();
    if (t < 64){
        float s = bd2[t];
        for (int i = 0; i < 64; i++) s += g2[i] * Wd2[i * 64 + t];
        g3[t] = seluf(s);
    }
    __syncthreads();
    if (t == 0){
        float l0 = bo[0], l1 = bo[1];
        for (int i = 0; i < 64; i++){ l0 += g3[i] * Wo[i * 2]; l1 += g3[i] * Wo[i * 2 + 1]; }
        float mx = fmaxf(l0, l1);
        float e0 = expf(l0 - mx), e1 = expf(l1 - mx);
        float inv = 1.f / (e0 + e1);
        out[g * 2] = e0 * inv;
        out[g * 2 + 1] = e1 * inv;
    }
}

extern "C" void kernel_launch(void* const* d_in, const int* in_sizes, int n_in,
                              void* d_out, int out_size, void* d_ws, size_t ws_size,
                              hipStream_t stream){
    const float* x   = (const float*)d_in[0];
    const int*   ei  = (const int*)d_in[1];
    const float* gin = (const float*)d_in[2];
    const float* gn_w = (const float*)d_in[4];
    const float* gn_b = (const float*)d_in[5];
    const float* gn_ms = (const float*)d_in[6];
    const float* W1 = (const float*)d_in[7];
    const float* as1 = (const float*)d_in[8];
    const float* ad1 = (const float*)d_in[9];
    const float* b1 = (const float*)d_in[10];
    const float* W2 = (const float*)d_in[11];
    const float* as2 = (const float*)d_in[12];
    const float* ad2 = (const float*)d_in[13];
    const float* b2 = (const float*)d_in[14];
    const float* W3 = (const float*)d_in[15];
    const float* as3 = (const float*)d_in[16];
    const float* ad3 = (const float*)d_in[17];
    const float* b3 = (const float*)d_in[18];
    const float* bn_g = (const float*)d_in[19];
    const float* bn_b = (const float*)d_in[20];
    const float* bn_m = (const float*)d_in[21];
    const float* bn_v = (const float*)d_in[22];
    const float* Wd1 = (const float*)d_in[23];
    const float* bd1 = (const float*)d_in[24];
    const float* Wd2 = (const float*)d_in[25];
    const float* bd2 = (const float*)d_in[26];
    const float* Wo = (const float*)d_in[27];
    const float* bo = (const float*)d_in[28];
    float* out = (float*)d_out;

    const int* src = ei;
    const int* dst = ei + N_EDGES;

    char* ws = (char*)d_ws;
    size_t off = 0;
    auto alloc = [&](size_t bytes) -> void* {
        void* p = ws + off;
        off = (off + bytes + 255) & ~(size_t)255;
        return p;
    };
    int* counts     = (int*)alloc((size_t)N_NODES * 4);
    int* local_off  = (int*)alloc((size_t)N_NODES * 4);
    int* node_off   = (int*)alloc((size_t)N_NODES * 4);
    int* write_ptr  = (int*)alloc((size_t)N_NODES * 4);
    int* graph_tot  = (int*)alloc(512 * 4);
    int* graph_base = (int*)alloc(512 * 4);
    int* csr        = (int*)alloc((size_t)N_EDGES * 4);
    float* y        = (float*)alloc((size_t)N_NODES * F_IN * 4);
    unsigned short* wp2 = (unsigned short*)alloc((size_t)256 * 256 * 2);
    unsigned short* wp3 = (unsigned short*)alloc((size_t)256 * 64 * 2);
    float* bufA     = (float*)alloc((size_t)N_NODES * 256 * 4);          // h (fp32 GEMM out)
    unsigned short* xb = (unsigned short*)alloc((size_t)N_ROWS_PAD * 256 * 2); // bf16 GEMM input
    float* bufC     = (float*)alloc((size_t)N_NODES * HID * 4);          // conv3 gemm out
    float* bufD     = (float*)alloc((size_t)N_NODES * HID * 4);          // conv3 agg out

    // --- CSR build ---
    hipMemsetAsync(counts, 0, (size_t)N_NODES * 4, stream);
    k_count<<<(N_EDGES + 255) / 256, 256, 0, stream>>>(dst, counts);
    k_local_scan<<<N_GRAPHS, 128, 0, stream>>>(counts, local_off, graph_tot);
    k_graph_scan<<<1, 512, 0, stream>>>(graph_tot, graph_base);
    k_off<<<(N_NODES + 255) / 256, 256, 0, stream>>>(local_off, graph_base, node_off, write_ptr);
    k_scatter<<<(N_EDGES + 255) / 256, 256, 0, stream>>>(src, dst, write_ptr, csr);

    // --- weight packs (bf16, MFMA-B order) ---
    k_pack_w<<<(256 * 256 + 255) / 256, 256, 0, stream>>>(W2, wp2, 256, 256);
    k_pack_w<<<(256 * 64 + 255) / 256, 256, 0, stream>>>(W3, wp3, 256, 64);

    // --- GraphNorm ---
    k_gnorm<<<N_GRAPHS, 256, 0, stream>>>(x, gn_w, gn_b, gn_ms, y);

    dim3 gemm_grid4(4, (N_NODES + 63) / 64);
    dim3 mfma_grid4(4, N_ROWS_PAD / 64);
    dim3 mfma_grid1(1, N_ROWS_PAD / 64);

    // --- conv1: 16 -> 4x64, ELU ---
    k_gemm_tiled<<<gemm_grid4, 256, 0, stream>>>(y, W1, bufA, N_NODES, 16, 256);
    k_fused4h<<<N_GRAPHS * 4, 256, 0, stream>>>(bufA, as1, ad1, b1, csr, node_off, counts, xb);

    // --- conv2: 256 -> 4x64, ELU ---
    k_gemm_mfma<<<mfma_grid4, 256, 0, stream>>>(xb, wp2, bufA, N_NODES, 256, 256);
    k_fused4h<<<N_GRAPHS * 4, 256, 0, stream>>>(bufA, as2, ad2, b2, csr, node_off, counts, xb);

    // --- conv3: 256 -> 64, no ELU ---
    k_gemm_mfma<<<mfma_grid1, 256, 0, stream>>>(xb, wp3, bufC, N_NODES, 256, 64);
    k_fused1<<<N_GRAPHS, 256, 0, stream>>>(bufC, as3, ad3, b3, csr, node_off, counts, bufD);

    // --- pool + BN + dense head + softmax ---
    k_head<<<N_GRAPHS, 256, 0, stream>>>(bufD, gin, bn_g, bn_b, bn_m, bn_v,
                                         Wd1, bd1, Wd2, bd2, Wo, bo, out);
}

// Round 7
// 424.563 us; speedup vs baseline: 1.2865x; 1.2865x over previous
//
#include <hip/hip_runtime.h>
#include <math.h>

#define N_NODES 50000
#define N_ROWS_PAD 50048   // 782 * 64
#define N_GRAPHS 500
#define NPG 100
#define N_EDGES 500000
#define F_IN 16
#define HID 64
#define EW_CAP 1408        // max intra-graph edges (mean 1000, sigma ~32 -> +12.9 sigma)

#define SELU_SCALE 1.0507009873554804934193349852946f
#define SELU_ALPHA 1.6732632423543772848170429916717f

typedef __attribute__((ext_vector_type(8))) short short8;
typedef __attribute__((ext_vector_type(4))) float floatx4;

__device__ __forceinline__ float lrelu(float x){ return x > 0.f ? x : 0.2f * x; }
__device__ __forceinline__ float eluf(float x){ return x > 0.f ? x : expf(x) - 1.f; }
__device__ __forceinline__ float seluf(float x){
    return x > 0.f ? SELU_SCALE * x : SELU_SCALE * (SELU_ALPHA * (expf(x) - 1.f));
}
__device__ __forceinline__ unsigned short f2bf(float x){
    unsigned u = __float_as_uint(x);
    return (unsigned short)((u + 0x7FFFu + ((u >> 16) & 1u)) >> 16);
}
__device__ __forceinline__ float bf2f(unsigned short u){
    return __uint_as_float((unsigned)u << 16);
}

// ---------------- CSR build ----------------
__global__ void k_count(const int* __restrict__ dst, int* __restrict__ counts){
    int e = blockIdx.x * 256 + threadIdx.x;
    if (e < N_EDGES) atomicAdd(&counts[dst[e]], 1);
}

__global__ void k_local_scan(const int* __restrict__ counts, int* __restrict__ local_off,
                             int* __restrict__ graph_tot){
    __shared__ int s[128];
    int g = blockIdx.x, t = threadIdx.x;
    int v = (t < NPG) ? counts[g * NPG + t] : 0;
    s[t] = v; __syncthreads();
    for (int o = 1; o < 128; o <<= 1){
        int x = (t >= o) ? s[t - o] : 0;
        __syncthreads();
        s[t] += x;
        __syncthreads();
    }
    if (t < NPG) local_off[g * NPG + t] = s[t] - v;   // exclusive
    if (t == 127) graph_tot[g] = s[127];
}

__global__ void k_graph_scan(const int* __restrict__ graph_tot, int* __restrict__ graph_base){
    __shared__ int s[512];
    int t = threadIdx.x;
    int v = (t < N_GRAPHS) ? graph_tot[t] : 0;
    s[t] = v; __syncthreads();
    for (int o = 1; o < 512; o <<= 1){
        int x = (t >= o) ? s[t - o] : 0;
        __syncthreads();
        s[t] += x;
        __syncthreads();
    }
    if (t < N_GRAPHS) graph_base[t] = s[t] - v;       // exclusive
}

__global__ void k_off(const int* __restrict__ local_off, const int* __restrict__ graph_base,
                      int* __restrict__ node_off, int* __restrict__ write_ptr){
    int n = blockIdx.x * 256 + threadIdx.x;
    if (n < N_NODES){
        int v = local_off[n] + graph_base[n / NPG];
        node_off[n] = v;
        write_ptr[n] = v;
    }
}

__global__ void k_scatter(const int* __restrict__ src, const int* __restrict__ dst,
                          int* __restrict__ write_ptr, int* __restrict__ csr){
    int e = blockIdx.x * 256 + threadIdx.x;
    if (e < N_EDGES){
        int d = dst[e];
        int pos = atomicAdd(&write_ptr[d], 1);
        csr[pos] = src[e];
    }
}

// ---------------- GraphNorm ----------------
__global__ void k_gnorm(const float* __restrict__ x, const float* __restrict__ w,
                        const float* __restrict__ b, const float* __restrict__ ms,
                        float* __restrict__ y){
    __shared__ float sx[NPG * F_IN];
    __shared__ float red[16][16];
    __shared__ float meanS[16], varS[16];
    int g = blockIdx.x, t = threadIdx.x;
    for (int idx = t; idx < NPG * F_IN; idx += 256) sx[idx] = x[g * NPG * F_IN + idx];
    __syncthreads();
    int f = t & 15, grp = t >> 4;
    float p = 0.f;
    for (int i = grp; i < NPG; i += 16) p += sx[i * 16 + f];
    red[grp][f] = p; __syncthreads();
    if (t < 16){
        float s = 0.f;
        for (int i = 0; i < 16; i++) s += red[i][t];
        meanS[t] = s * (1.f / 100.f);
    }
    __syncthreads();
    float mm = meanS[f] * ms[f];
    p = 0.f;
    for (int i = grp; i < NPG; i += 16){ float v = sx[i * 16 + f] - mm; p += v * v; }
    red[grp][f] = p; __syncthreads();
    if (t < 16){
        float s = 0.f;
        for (int i = 0; i < 16; i++) s += red[i][t];
        varS[t] = s * (1.f / 100.f);
    }
    __syncthreads();
    for (int idx = t; idx < NPG * F_IN; idx += 256){
        int ff = idx & 15;
        float v = sx[idx] - meanS[ff] * ms[ff];
        y[g * NPG * F_IN + idx] = w[ff] * v * rsqrtf(varS[ff] + 1e-5f) + b[ff];
    }
}

// ---------------- fp32 tiled GEMM (conv1 only, K=16) ----------------
__global__ void k_gemm_tiled(const float* __restrict__ X, const float* __restrict__ W,
                             float* __restrict__ Y, int N, int K, int OUT){
    __shared__ float As[16][68];
    __shared__ float Bs[16][68];
    int t = threadIdx.x;
    int r0 = blockIdx.y * 64;
    int c0 = blockIdx.x * 64;
    int tx = t & 15, ty = t >> 4;
    float acc[4][4];
    #pragma unroll
    for (int i = 0; i < 4; i++)
        #pragma unroll
        for (int j = 0; j < 4; j++) acc[i][j] = 0.f;

    int lk = t & 15;
    int lm0 = t >> 4;
    int ln = t & 63;
    int lkb = t >> 6;

    for (int kt = 0; kt < K; kt += 16){
        #pragma unroll
        for (int i = 0; i < 4; i++){
            int m = lm0 + i * 16;
            int row = r0 + m;
            As[lk][m] = (row < N) ? X[row * K + kt + lk] : 0.f;
        }
        #pragma unroll
        for (int i = 0; i < 4; i++){
            int k = lkb + i * 4;
            Bs[k][ln] = W[(kt + k) * OUT + c0 + ln];
        }
        __syncthreads();
        #pragma unroll
        for (int k = 0; k < 16; k++){
            float4 a = *(const float4*)&As[k][ty * 4];
            float4 b = *(const float4*)&Bs[k][tx * 4];
            float av[4] = {a.x, a.y, a.z, a.w};
            float bv[4] = {b.x, b.y, b.z, b.w};
            #pragma unroll
            for (int i = 0; i < 4; i++)
                #pragma unroll
                for (int j = 0; j < 4; j++) acc[i][j] += av[i] * bv[j];
        }
        __syncthreads();
    }
    #pragma unroll
    for (int i = 0; i < 4; i++){
        int row = r0 + ty * 4 + i;
        if (row < N){
            float4 v = make_float4(acc[i][0], acc[i][1], acc[i][2], acc[i][3]);
            *(float4*)&Y[row * OUT + c0 + tx * 4] = v;
        }
    }
}

// ---------------- W pack to MFMA-B-fragment order + bf16 ----------------
__global__ void k_pack_w(const float* __restrict__ W, unsigned short* __restrict__ Wp,
                         int K, int OUT){
    int idx = blockIdx.x * 256 + threadIdx.x;
    if (idx >= K * OUT) return;
    int k = idx / OUT, n = idx - k * OUT;
    Wp[(((k >> 3) * OUT) + n) * 8 + (k & 7)] = f2bf(W[idx]);
}

// ---------------- bf16 MFMA GEMM ----------------
__global__ void k_gemm_mfma(const unsigned short* __restrict__ Xb,
                            const unsigned short* __restrict__ Wp,
                            float* __restrict__ Y, int N, int K, int OUT){
    int t = threadIdx.x;
    int wave = t >> 6, lane = t & 63;
    int quad = lane >> 4, ln = lane & 15;
    int r0 = blockIdx.y * 64 + wave * 16;
    int c0 = blockIdx.x * 64;

    floatx4 acc[4];
    #pragma unroll
    for (int f = 0; f < 4; f++) acc[f] = (floatx4){0.f, 0.f, 0.f, 0.f};

    const unsigned short* aptr = Xb + (size_t)(r0 + ln) * K + quad * 8;
    for (int kt = 0; kt < K; kt += 32){
        short8 a = *(const short8*)(aptr + kt);
        int kc = (kt >> 3) + quad;
        #pragma unroll
        for (int f = 0; f < 4; f++){
            short8 b = *(const short8*)(Wp + ((size_t)kc * OUT + c0 + f * 16 + ln) * 8);
            acc[f] = __builtin_amdgcn_mfma_f32_16x16x32_bf16(a, b, acc[f], 0, 0, 0);
        }
    }
    int rowb = r0 + quad * 4;
    #pragma unroll
    for (int f = 0; f < 4; f++){
        int col = c0 + f * 16 + ln;
        #pragma unroll
        for (int rg = 0; rg < 4; rg++){
            int row = rowb + rg;
            if (row < N) Y[(size_t)row * OUT + col] = acc[f][rg];
        }
    }
}

// ---------------- fused GAT layer, one block (512 thr = 8 waves) per graph ----
// H=4, C=64. h fp32 in (global), bf16 out, ELU applied.
// LDS ~75 KB -> 2 blocks/CU = 16 waves/CU.
__global__ void __launch_bounds__(512)
k_fused4(const float* __restrict__ h, const float* __restrict__ as,
         const float* __restrict__ ad, const float* __restrict__ bias,
         const int* __restrict__ csr, const int* __restrict__ noff,
         const int* __restrict__ cnt, unsigned short* __restrict__ out_bf){
    __shared__ __align__(16) unsigned short hl[NPG * 256];   // 51200 B (bf16)
    __shared__ __align__(8)  unsigned short ewl[EW_CAP * 4]; // 11264 B (bf16)
    __shared__ int   csl[EW_CAP];                            // 5632 B
    __shared__ __align__(16) float asrcl[NPG * 4], adstl[NPG * 4];   // 3200 B
    __shared__ __align__(16) float wselfl[NPG * 4], rsuml[NPG * 4];  // 3200 B
    __shared__ int offl[NPG], cntl[NPG];                     // 800 B

    int g = blockIdx.x, t = threadIdx.x;
    int wave = t >> 6, lane = t & 63;
    int base = g * NPG;

    // uniform CSR bounds (scalar loads, no LDS dependency)
    int ebeg = noff[base];
    int etot = noff[base + NPG - 1] + cnt[base + NPG - 1] - ebeg;
    int eln = etot < EW_CAP ? etot : EW_CAP;

    // phase 0a: stage hl (fp32 global -> bf16 LDS)
    const float4* hsrc = (const float4*)(h + (size_t)base * 256);
    for (int i = t; i < NPG * 64; i += 512){
        float4 v = hsrc[i];
        ushort4 u;
        u.x = f2bf(v.x); u.y = f2bf(v.y); u.z = f2bf(v.z); u.w = f2bf(v.w);
        *(ushort4*)&hl[i * 4] = u;
    }
    // phase 0b: stage CSR slice (localized ids) + per-node offsets
    for (int i = t; i < eln; i += 512) csl[i] = csr[ebeg + i] - base;
    if (t < NPG){ offl[t] = noff[base + t]; cntl[t] = cnt[base + t]; }

    // phase 0c: logits from fp32 GLOBAL (exact), one wave per node
    float asr[4], adr[4];
    #pragma unroll
    for (int k = 0; k < 4; k++){ asr[k] = as[k * 64 + lane]; adr[k] = ad[k * 64 + lane]; }
    for (int n = wave; n < NPG; n += 8){
        const float* hr = h + (size_t)(base + n) * 256;
        float ps[4], pd[4];
        #pragma unroll
        for (int k = 0; k < 4; k++){
            float v = hr[k * 64 + lane];
            ps[k] = v * asr[k];
            pd[k] = v * adr[k];
        }
        #pragma unroll
        for (int o = 32; o >= 1; o >>= 1){
            #pragma unroll
            for (int k = 0; k < 4; k++){
                ps[k] += __shfl_xor(ps[k], o);
                pd[k] += __shfl_xor(pd[k], o);
            }
        }
        if (lane == 0){
            *(float4*)&asrcl[n * 4] = make_float4(ps[0], ps[1], ps[2], ps[3]);
            *(float4*)&adstl[n * 4] = make_float4(pd[0], pd[1], pd[2], pd[3]);
        }
    }
    __syncthreads();

    // phase 1: softmax weights, one THREAD per dst node; no max-sub (logits bounded)
    if (t < NPG){
        float4 adv = *(const float4*)&adstl[t * 4];
        float4 asv = *(const float4*)&asrcl[t * 4];
        float w0 = expf(lrelu(asv.x + adv.x));
        float w1 = expf(lrelu(asv.y + adv.y));
        float w2 = expf(lrelu(asv.z + adv.z));
        float w3 = expf(lrelu(asv.w + adv.w));
        float s0 = w0, s1 = w1, s2 = w2, s3 = w3;
        int ebg = offl[t] - ebeg, n = cntl[t];
        for (int j = 0; j < n; j++){
            int s = csl[ebg + j];
            float4 av = *(const float4*)&asrcl[s * 4];
            ushort4 u;
            u.x = f2bf(expf(lrelu(av.x + adv.x)));
            u.y = f2bf(expf(lrelu(av.y + adv.y)));
            u.z = f2bf(expf(lrelu(av.z + adv.z)));
            u.w = f2bf(expf(lrelu(av.w + adv.w)));
            *(ushort4*)&ewl[(ebg + j) * 4] = u;
            s0 += bf2f(u.x); s1 += bf2f(u.y); s2 += bf2f(u.z); s3 += bf2f(u.w);
        }
        *(float4*)&wselfl[t * 4] = make_float4(w0, w1, w2, w3);
        *(float4*)&rsuml[t * 4] = make_float4(1.f / s0, 1.f / s1, 1.f / s2, 1.f / s3);
    }
    __syncthreads();

    // phase 2: aggregate, one WAVE per dst node
    float b0 = bias[lane], b1 = bias[64 + lane], b2 = bias[128 + lane], b3 = bias[192 + lane];
    for (int d = wave; d < NPG; d += 8){
        float4 ws = *(const float4*)&wselfl[d * 4];
        float4 rs = *(const float4*)&rsuml[d * 4];
        const unsigned short* hr = &hl[d * 256];
        float a0 = ws.x * bf2f(hr[lane]);
        float a1 = ws.y * bf2f(hr[64 + lane]);
        float a2 = ws.z * bf2f(hr[128 + lane]);
        float a3 = ws.w * bf2f(hr[192 + lane]);
        int ebg = offl[d] - ebeg, n = cntl[d];
        for (int j = 0; j < n; j++){
            int s = csl[ebg + j];
            ushort4 w = *(const ushort4*)&ewl[(ebg + j) * 4];
            const unsigned short* hs = &hl[s * 256];
            a0 = fmaf(bf2f(w.x), bf2f(hs[lane]),       a0);
            a1 = fmaf(bf2f(w.y), bf2f(hs[64 + lane]),  a1);
            a2 = fmaf(bf2f(w.z), bf2f(hs[128 + lane]), a2);
            a3 = fmaf(bf2f(w.w), bf2f(hs[192 + lane]), a3);
        }
        size_t ob = (size_t)(base + d) * 256 + lane;
        out_bf[ob]       = f2bf(eluf(a0 * rs.x + b0));
        out_bf[ob + 64]  = f2bf(eluf(a1 * rs.y + b1));
        out_bf[ob + 128] = f2bf(eluf(a2 * rs.z + b2));
        out_bf[ob + 192] = f2bf(eluf(a3 * rs.w + b3));
    }
}

// H=1, C=64, one block (256 thr) per graph, fp32 out, no ELU (conv3 -> head).
// LDS ~24 KB -> ~6 blocks/CU.
__global__ void __launch_bounds__(256)
k_fused1(const float* __restrict__ h, const float* __restrict__ as,
         const float* __restrict__ ad, const float* __restrict__ bias,
         const int* __restrict__ csr, const int* __restrict__ noff,
         const int* __restrict__ cnt, float* __restrict__ out){
    __shared__ __align__(16) unsigned short hl[NPG * 64];  // 12800 B
    __shared__ unsigned short ewl[EW_CAP];                 // 2816 B
    __shared__ int   csl[EW_CAP];                          // 5632 B
    __shared__ float asrcl[NPG], adstl[NPG];
    __shared__ float wselfl[NPG], rsuml[NPG];
    __shared__ int offl[NPG], cntl[NPG];

    int g = blockIdx.x, t = threadIdx.x;
    int wave = t >> 6, lane = t & 63;
    int base = g * NPG;

    int ebeg = noff[base];
    int etot = noff[base + NPG - 1] + cnt[base + NPG - 1] - ebeg;
    int eln = etot < EW_CAP ? etot : EW_CAP;

    const float4* hsrc = (const float4*)(h + (size_t)base * 64);
    for (int i = t; i < NPG * 16; i += 256){
        float4 v = hsrc[i];
        ushort4 u;
        u.x = f2bf(v.x); u.y = f2bf(v.y); u.z = f2bf(v.z); u.w = f2bf(v.w);
        *(ushort4*)&hl[i * 4] = u;
    }
    for (int i = t; i < eln; i += 256) csl[i] = csr[ebeg + i] - base;
    if (t < NPG){ offl[t] = noff[base + t]; cntl[t] = cnt[base + t]; }

    float asr = as[lane], adr = ad[lane];
    for (int n = wave; n < NPG; n += 4){
        float v = h[(size_t)(base + n) * 64 + lane];
        float ps = v * asr, pd = v * adr;
        #pragma unroll
        for (int o = 32; o >= 1; o >>= 1){
            ps += __shfl_xor(ps, o);
            pd += __shfl_xor(pd, o);
        }
        if (lane == 0){ asrcl[n] = ps; adstl[n] = pd; }
    }
    __syncthreads();

    if (t < NPG){
        float adv = adstl[t];
        float wsf = expf(lrelu(asrcl[t] + adv));
        float sum = wsf;
        int ebg = offl[t] - ebeg, n = cntl[t];
        for (int j = 0; j < n; j++){
            int s = csl[ebg + j];
            unsigned short u = f2bf(expf(lrelu(asrcl[s] + adv)));
            ewl[ebg + j] = u;
            sum += bf2f(u);
        }
        wselfl[t] = wsf;
        rsuml[t] = 1.f / sum;
    }
    __syncthreads();

    float bl = bias[lane];
    for (int d = wave; d < NPG; d += 4){
        float acc = wselfl[d] * bf2f(hl[d * 64 + lane]);
        int ebg = offl[d] - ebeg, n = cntl[d];
        for (int j = 0; j < n; j++){
            int s = csl[ebg + j];
            acc = fmaf(bf2f(ewl[ebg + j]), bf2f(hl[s * 64 + lane]), acc);
        }
        out[(size_t)(base + d) * 64 + lane] = acc * rsuml[d] + bl;
    }
}

// ---------------- pooling + BN + dense head ----------------
__global__ void k_head(const float* __restrict__ x3, const float* __restrict__ gin,
                       const float* __restrict__ bn_g, const float* __restrict__ bn_b,
                       const float* __restrict__ bn_m, const float* __restrict__ bn_v,
                       const float* __restrict__ Wd1, const float* __restrict__ bd1,
                       const float* __restrict__ Wd2, const float* __restrict__ bd2,
                       const float* __restrict__ Wo, const float* __restrict__ bo,
                       float* __restrict__ out){
    __shared__ float red[256];
    __shared__ float gv[68];
    __shared__ float g2[64];
    __shared__ float g3[64];
    int g = blockIdx.x, t = threadIdx.x;
    int c = t & 63, grp = t >> 6;
    float p = 0.f;
    for (int i = grp; i < NPG; i += 4) p += x3[(g * NPG + i) * 64 + c];
    red[t] = p; __syncthreads();
    if (t < 64){
        float s = red[t] + red[t + 64] + red[t + 128] + red[t + 192];
        float mean = s * (1.f / 100.f);
        gv[t] = (mean - bn_m[t]) * rsqrtf(bn_v[t] + 1e-5f) * bn_g[t] + bn_b[t];
    } else if (t < 68){
        int j = t - 64;
        float v = gin[g * 4 + j];
        gv[t] = (v - bn_m[t]) * rsqrtf(bn_v[t] + 1e-5f) * bn_g[t] + bn_b[t];
    }
    __syncthreads();
    if (t < 64){
        float s = bd1[t];
        for (int i = 0; i < 68; i++) s += gv[i] * Wd1[i * 64 + t];
        g2[t] = seluf(s);
    }
    __syncthreads();
    if (t < 64){
        float s = bd2[t];
        for (int i = 0; i < 64; i++) s += g2[i] * Wd2[i * 64 + t];
        g3[t] = seluf(s);
    }
    __syncthreads();
    if (t == 0){
        float l0 = bo[0], l1 = bo[1];
        for (int i = 0; i < 64; i++){ l0 += g3[i] * Wo[i * 2]; l1 += g3[i] * Wo[i * 2 + 1]; }
        float mx = fmaxf(l0, l1);
        float e0 = expf(l0 - mx), e1 = expf(l1 - mx);
        float inv = 1.f / (e0 + e1);
        out[g * 2] = e0 * inv;
        out[g * 2 + 1] = e1 * inv;
    }
}

extern "C" void kernel_launch(void* const* d_in, const int* in_sizes, int n_in,
                              void* d_out, int out_size, void* d_ws, size_t ws_size,
                              hipStream_t stream){
    const float* x   = (const float*)d_in[0];
    const int*   ei  = (const int*)d_in[1];
    const float* gin = (const float*)d_in[2];
    const float* gn_w = (const float*)d_in[4];
    const float* gn_b = (const float*)d_in[5];
    const float* gn_ms = (const float*)d_in[6];
    const float* W1 = (const float*)d_in[7];
    const float* as1 = (const float*)d_in[8];
    const float* ad1 = (const float*)d_in[9];
    const float* b1 = (const float*)d_in[10];
    const float* W2 = (const float*)d_in[11];
    const float* as2 = (const float*)d_in[12];
    const float* ad2 = (const float*)d_in[13];
    const float* b2 = (const float*)d_in[14];
    const float* W3 = (const float*)d_in[15];
    const float* as3 = (const float*)d_in[16];
    const float* ad3 = (const float*)d_in[17];
    const float* b3 = (const float*)d_in[18];
    const float* bn_g = (const float*)d_in[19];
    const float* bn_b = (const float*)d_in[20];
    const float* bn_m = (const float*)d_in[21];
    const float* bn_v = (const float*)d_in[22];
    const float* Wd1 = (const float*)d_in[23];
    const float* bd1 = (const float*)d_in[24];
    const float* Wd2 = (const float*)d_in[25];
    const float* bd2 = (const float*)d_in[26];
    const float* Wo = (const float*)d_in[27];
    const float* bo = (const float*)d_in[28];
    float* out = (float*)d_out;

    const int* src = ei;
    const int* dst = ei + N_EDGES;

    char* ws = (char*)d_ws;
    size_t off = 0;
    auto alloc = [&](size_t bytes) -> void* {
        void* p = ws + off;
        off = (off + bytes + 255) & ~(size_t)255;
        return p;
    };
    int* counts     = (int*)alloc((size_t)N_NODES * 4);
    int* local_off  = (int*)alloc((size_t)N_NODES * 4);
    int* node_off   = (int*)alloc((size_t)N_NODES * 4);
    int* write_ptr  = (int*)alloc((size_t)N_NODES * 4);
    int* graph_tot  = (int*)alloc(512 * 4);
    int* graph_base = (int*)alloc(512 * 4);
    int* csr        = (int*)alloc((size_t)N_EDGES * 4);
    float* y        = (float*)alloc((size_t)N_NODES * F_IN * 4);
    unsigned short* wp2 = (unsigned short*)alloc((size_t)256 * 256 * 2);
    unsigned short* wp3 = (unsigned short*)alloc((size_t)256 * 64 * 2);
    float* bufA     = (float*)alloc((size_t)N_NODES * 256 * 4);          // h (fp32 GEMM out)
    unsigned short* xb = (unsigned short*)alloc((size_t)N_ROWS_PAD * 256 * 2); // bf16 GEMM input
    float* bufC     = (float*)alloc((size_t)N_NODES * HID * 4);          // conv3 gemm out
    float* bufD     = (float*)alloc((size_t)N_NODES * HID * 4);          // conv3 agg out

    // --- CSR build ---
    hipMemsetAsync(counts, 0, (size_t)N_NODES * 4, stream);
    k_count<<<(N_EDGES + 255) / 256, 256, 0, stream>>>(dst, counts);
    k_local_scan<<<N_GRAPHS, 128, 0, stream>>>(counts, local_off, graph_tot);
    k_graph_scan<<<1, 512, 0, stream>>>(graph_tot, graph_base);
    k_off<<<(N_NODES + 255) / 256, 256, 0, stream>>>(local_off, graph_base, node_off, write_ptr);
    k_scatter<<<(N_EDGES + 255) / 256, 256, 0, stream>>>(src, dst, write_ptr, csr);

    // --- weight packs (bf16, MFMA-B order) ---
    k_pack_w<<<(256 * 256 + 255) / 256, 256, 0, stream>>>(W2, wp2, 256, 256);
    k_pack_w<<<(256 * 64 + 255) / 256, 256, 0, stream>>>(W3, wp3, 256, 64);

    // --- GraphNorm ---
    k_gnorm<<<N_GRAPHS, 256, 0, stream>>>(x, gn_w, gn_b, gn_ms, y);

    dim3 gemm_grid4(4, (N_NODES + 63) / 64);
    dim3 mfma_grid4(4, N_ROWS_PAD / 64);
    dim3 mfma_grid1(1, N_ROWS_PAD / 64);

    // --- conv1: 16 -> 4x64, ELU ---
    k_gemm_tiled<<<gemm_grid4, 256, 0, stream>>>(y, W1, bufA, N_NODES, 16, 256);
    k_fused4<<<N_GRAPHS, 512, 0, stream>>>(bufA, as1, ad1, b1, csr, node_off, counts, xb);

    // --- conv2: 256 -> 4x64, ELU ---
    k_gemm_mfma<<<mfma_grid4, 256, 0, stream>>>(xb, wp2, bufA, N_NODES, 256, 256);
    k_fused4<<<N_GRAPHS, 512, 0, stream>>>(bufA, as2, ad2, b2, csr, node_off, counts, xb);

    // --- conv3: 256 -> 64, no ELU ---
    k_gemm_mfma<<<mfma_grid1, 256, 0, stream>>>(xb, wp3, bufC, N_NODES, 256, 64);
    k_fused1<<<N_GRAPHS, 256, 0, stream>>>(bufC, as3, ad3, b3, csr, node_off, counts, bufD);

    // --- pool + BN + dense head + softmax ---
    k_head<<<N_GRAPHS, 256, 0, stream>>>(bufD, gin, bn_g, bn_b, bn_m, bn_v,
                                         Wd1, bd1, Wd2, bd2, Wo, bo, out);
}

// Round 8
// 403.109 us; speedup vs baseline: 1.3550x; 1.0532x over previous
//
#include <hip/hip_runtime.h>
#include <math.h>

#define N_NODES 50000
#define N_ROWS_PAD 50048   // 782 * 64
#define N_GRAPHS 500
#define NPG 100
#define N_EDGES 500000
#define F_IN 16
#define HID 64
#define EW_CAP 1408        // max intra-graph edges (mean 1000, sigma ~32 -> +12.9 sigma)

#define SELU_SCALE 1.0507009873554804934193349852946f
#define SELU_ALPHA 1.6732632423543772848170429916717f

typedef __attribute__((ext_vector_type(8))) short short8;
typedef __attribute__((ext_vector_type(4))) float floatx4;

__device__ __forceinline__ float lrelu(float x){ return x > 0.f ? x : 0.2f * x; }
__device__ __forceinline__ float eluf(float x){ return x > 0.f ? x : expf(x) - 1.f; }
__device__ __forceinline__ float seluf(float x){
    return x > 0.f ? SELU_SCALE * x : SELU_SCALE * (SELU_ALPHA * (expf(x) - 1.f));
}
__device__ __forceinline__ unsigned short f2bf(float x){
    unsigned u = __float_as_uint(x);
    return (unsigned short)((u + 0x7FFFu + ((u >> 16) & 1u)) >> 16);
}
__device__ __forceinline__ float bf2f(unsigned short u){
    return __uint_as_float((unsigned)u << 16);
}

// ---------------- CSR build ----------------
__global__ void k_count(const int* __restrict__ dst, int* __restrict__ counts){
    int e = blockIdx.x * 256 + threadIdx.x;
    if (e < N_EDGES) atomicAdd(&counts[dst[e]], 1);
}

__global__ void k_local_scan(const int* __restrict__ counts, int* __restrict__ local_off,
                             int* __restrict__ graph_tot){
    __shared__ int s[128];
    int g = blockIdx.x, t = threadIdx.x;
    int v = (t < NPG) ? counts[g * NPG + t] : 0;
    s[t] = v; __syncthreads();
    for (int o = 1; o < 128; o <<= 1){
        int x = (t >= o) ? s[t - o] : 0;
        __syncthreads();
        s[t] += x;
        __syncthreads();
    }
    if (t < NPG) local_off[g * NPG + t] = s[t] - v;   // exclusive
    if (t == 127) graph_tot[g] = s[127];
}

__global__ void k_graph_scan(const int* __restrict__ graph_tot, int* __restrict__ graph_base){
    __shared__ int s[512];
    int t = threadIdx.x;
    int v = (t < N_GRAPHS) ? graph_tot[t] : 0;
    s[t] = v; __syncthreads();
    for (int o = 1; o < 512; o <<= 1){
        int x = (t >= o) ? s[t - o] : 0;
        __syncthreads();
        s[t] += x;
        __syncthreads();
    }
    if (t < N_GRAPHS) graph_base[t] = s[t] - v;       // exclusive
}

__global__ void k_off(const int* __restrict__ local_off, const int* __restrict__ graph_base,
                      int* __restrict__ node_off, int* __restrict__ write_ptr){
    int n = blockIdx.x * 256 + threadIdx.x;
    if (n < N_NODES){
        int v = local_off[n] + graph_base[n / NPG];
        node_off[n] = v;
        write_ptr[n] = v;
    }
}

__global__ void k_scatter(const int* __restrict__ src, const int* __restrict__ dst,
                          int* __restrict__ write_ptr, int* __restrict__ csr){
    int e = blockIdx.x * 256 + threadIdx.x;
    if (e < N_EDGES){
        int d = dst[e];
        int pos = atomicAdd(&write_ptr[d], 1);
        csr[pos] = src[e];
    }
}

// ---------------- GraphNorm ----------------
__global__ void k_gnorm(const float* __restrict__ x, const float* __restrict__ w,
                        const float* __restrict__ b, const float* __restrict__ ms,
                        float* __restrict__ y){
    __shared__ float sx[NPG * F_IN];
    __shared__ float red[16][16];
    __shared__ float meanS[16], varS[16];
    int g = blockIdx.x, t = threadIdx.x;
    for (int idx = t; idx < NPG * F_IN; idx += 256) sx[idx] = x[g * NPG * F_IN + idx];
    __syncthreads();
    int f = t & 15, grp = t >> 4;
    float p = 0.f;
    for (int i = grp; i < NPG; i += 16) p += sx[i * 16 + f];
    red[grp][f] = p; __syncthreads();
    if (t < 16){
        float s = 0.f;
        for (int i = 0; i < 16; i++) s += red[i][t];
        meanS[t] = s * (1.f / 100.f);
    }
    __syncthreads();
    float mm = meanS[f] * ms[f];
    p = 0.f;
    for (int i = grp; i < NPG; i += 16){ float v = sx[i * 16 + f] - mm; p += v * v; }
    red[grp][f] = p; __syncthreads();
    if (t < 16){
        float s = 0.f;
        for (int i = 0; i < 16; i++) s += red[i][t];
        varS[t] = s * (1.f / 100.f);
    }
    __syncthreads();
    for (int idx = t; idx < NPG * F_IN; idx += 256){
        int ff = idx & 15;
        float v = sx[idx] - meanS[ff] * ms[ff];
        y[g * NPG * F_IN + idx] = w[ff] * v * rsqrtf(varS[ff] + 1e-5f) + b[ff];
    }
}

// ---------------- fp32 tiled GEMM (conv1 only, K=16) ----------------
__global__ void k_gemm_tiled(const float* __restrict__ X, const float* __restrict__ W,
                             float* __restrict__ Y, int N, int K, int OUT){
    __shared__ float As[16][68];
    __shared__ float Bs[16][68];
    int t = threadIdx.x;
    int r0 = blockIdx.y * 64;
    int c0 = blockIdx.x * 64;
    int tx = t & 15, ty = t >> 4;
    float acc[4][4];
    #pragma unroll
    for (int i = 0; i < 4; i++)
        #pragma unroll
        for (int j = 0; j < 4; j++) acc[i][j] = 0.f;

    int lk = t & 15;
    int lm0 = t >> 4;
    int ln = t & 63;
    int lkb = t >> 6;

    for (int kt = 0; kt < K; kt += 16){
        #pragma unroll
        for (int i = 0; i < 4; i++){
            int m = lm0 + i * 16;
            int row = r0 + m;
            As[lk][m] = (row < N) ? X[row * K + kt + lk] : 0.f;
        }
        #pragma unroll
        for (int i = 0; i < 4; i++){
            int k = lkb + i * 4;
            Bs[k][ln] = W[(kt + k) * OUT + c0 + ln];
        }
        __syncthreads();
        #pragma unroll
        for (int k = 0; k < 16; k++){
            float4 a = *(const float4*)&As[k][ty * 4];
            float4 b = *(const float4*)&Bs[k][tx * 4];
            float av[4] = {a.x, a.y, a.z, a.w};
            float bv[4] = {b.x, b.y, b.z, b.w};
            #pragma unroll
            for (int i = 0; i < 4; i++)
                #pragma unroll
                for (int j = 0; j < 4; j++) acc[i][j] += av[i] * bv[j];
        }
        __syncthreads();
    }
    #pragma unroll
    for (int i = 0; i < 4; i++){
        int row = r0 + ty * 4 + i;
        if (row < N){
            float4 v = make_float4(acc[i][0], acc[i][1], acc[i][2], acc[i][3]);
            *(float4*)&Y[row * OUT + c0 + tx * 4] = v;
        }
    }
}

// ---------------- W pack to MFMA-B-fragment order + bf16 ----------------
__global__ void k_pack_w(const float* __restrict__ W, unsigned short* __restrict__ Wp,
                         int K, int OUT){
    int idx = blockIdx.x * 256 + threadIdx.x;
    if (idx >= K * OUT) return;
    int k = idx / OUT, n = idx - k * OUT;
    Wp[(((k >> 3) * OUT) + n) * 8 + (k & 7)] = f2bf(W[idx]);
}

// ---------------- bf16 MFMA GEMM ----------------
__global__ void k_gemm_mfma(const unsigned short* __restrict__ Xb,
                            const unsigned short* __restrict__ Wp,
                            float* __restrict__ Y, int N, int K, int OUT){
    int t = threadIdx.x;
    int wave = t >> 6, lane = t & 63;
    int quad = lane >> 4, ln = lane & 15;
    int r0 = blockIdx.y * 64 + wave * 16;
    int c0 = blockIdx.x * 64;

    floatx4 acc[4];
    #pragma unroll
    for (int f = 0; f < 4; f++) acc[f] = (floatx4){0.f, 0.f, 0.f, 0.f};

    const unsigned short* aptr = Xb + (size_t)(r0 + ln) * K + quad * 8;
    for (int kt = 0; kt < K; kt += 32){
        short8 a = *(const short8*)(aptr + kt);
        int kc = (kt >> 3) + quad;
        #pragma unroll
        for (int f = 0; f < 4; f++){
            short8 b = *(const short8*)(Wp + ((size_t)kc * OUT + c0 + f * 16 + ln) * 8);
            acc[f] = __builtin_amdgcn_mfma_f32_16x16x32_bf16(a, b, acc[f], 0, 0, 0);
        }
    }
    int rowb = r0 + quad * 4;
    #pragma unroll
    for (int f = 0; f < 4; f++){
        int col = c0 + f * 16 + ln;
        #pragma unroll
        for (int rg = 0; rg < 4; rg++){
            int row = rowb + rg;
            if (row < N) Y[(size_t)row * OUT + col] = acc[f][rg];
        }
    }
}

// ---------------- fused GAT layer, one block (512 thr = 8 waves) per graph ----
// H=4, C=64. h fp32 in (global), bf16 out, ELU applied.
// LDS layout hl[node][c][head] (head-interleaved) so one ds_read_b64 per lane
// covers all 4 heads of its channel. ~75 KB LDS -> 2 blocks/CU.
__global__ void __launch_bounds__(512)
k_fused4(const float* __restrict__ h, const float* __restrict__ as,
         const float* __restrict__ ad, const float* __restrict__ bias,
         const int* __restrict__ csr, const int* __restrict__ noff,
         const int* __restrict__ cnt, unsigned short* __restrict__ out_bf){
    __shared__ __align__(16) unsigned short hl[NPG * 256];   // [n][c][h] 51200 B
    __shared__ __align__(16) unsigned short ewl[EW_CAP * 4]; // [e][h]   11264 B
    __shared__ int   csl[EW_CAP];                            // 5632 B
    __shared__ __align__(16) float asrcl[NPG * 4], adstl[NPG * 4];   // [n][h]
    __shared__ __align__(16) float wselfl[NPG * 4], rsuml[NPG * 4];  // [n][h]
    __shared__ int offl[NPG], cntl[NPG];

    int g = blockIdx.x, t = threadIdx.x;
    int wave = t >> 6, lane = t & 63;
    int base = g * NPG;

    int ebeg = noff[base];
    int etot = noff[base + NPG - 1] + cnt[base + NPG - 1] - ebeg;
    int eln = etot < EW_CAP ? etot : EW_CAP;

    // phase 0a: stage hl with head-interleave transpose (fp32 global -> bf16 LDS)
    // work item i = (node, c4): reads float4 from each head, writes 4 ushort4.
    for (int i = t; i < NPG * 16; i += 512){
        int node = i >> 4, c4 = i & 15;
        const float* hr = h + (size_t)(base + node) * 256 + c4 * 4;
        float4 f0 = *(const float4*)(hr);
        float4 f1 = *(const float4*)(hr + 64);
        float4 f2 = *(const float4*)(hr + 128);
        float4 f3 = *(const float4*)(hr + 192);
        float a0[4] = {f0.x, f0.y, f0.z, f0.w};
        float a1[4] = {f1.x, f1.y, f1.z, f1.w};
        float a2[4] = {f2.x, f2.y, f2.z, f2.w};
        float a3[4] = {f3.x, f3.y, f3.z, f3.w};
        #pragma unroll
        for (int k = 0; k < 4; k++){
            ushort4 u;
            u.x = f2bf(a0[k]); u.y = f2bf(a1[k]); u.z = f2bf(a2[k]); u.w = f2bf(a3[k]);
            *(ushort4*)&hl[node * 256 + (c4 * 4 + k) * 4] = u;
        }
    }
    // phase 0b: stage CSR slice (localized ids) + per-node offsets
    for (int i = t; i < eln; i += 512) csl[i] = csr[ebeg + i] - base;
    if (t < NPG){ offl[t] = noff[base + t]; cntl[t] = cnt[base + t]; }
    __syncthreads();

    // phase 0c: logits from bf16 LDS, one wave per node, lane = channel
    float asr[4], adr[4];
    #pragma unroll
    for (int k = 0; k < 4; k++){ asr[k] = as[k * 64 + lane]; adr[k] = ad[k * 64 + lane]; }
    for (int n = wave; n < NPG; n += 8){
        ushort4 u = *(const ushort4*)&hl[n * 256 + lane * 4];
        float ps[4], pd[4];
        float hv[4] = {bf2f(u.x), bf2f(u.y), bf2f(u.z), bf2f(u.w)};
        #pragma unroll
        for (int k = 0; k < 4; k++){ ps[k] = hv[k] * asr[k]; pd[k] = hv[k] * adr[k]; }
        #pragma unroll
        for (int o = 32; o >= 1; o >>= 1){
            #pragma unroll
            for (int k = 0; k < 4; k++){
                ps[k] += __shfl_xor(ps[k], o);
                pd[k] += __shfl_xor(pd[k], o);
            }
        }
        if (lane == 0){
            *(float4*)&asrcl[n * 4] = make_float4(ps[0], ps[1], ps[2], ps[3]);
            *(float4*)&adstl[n * 4] = make_float4(pd[0], pd[1], pd[2], pd[3]);
        }
    }
    __syncthreads();

    // phase 1: softmax weights, one thread per (dst, head) = 400 threads
    if (t < NPG * 4){
        int d = t >> 2, hh = t & 3;
        float adv = adstl[d * 4 + hh];
        float wsf = expf(lrelu(asrcl[d * 4 + hh] + adv));
        float sum = wsf;
        int ebg = offl[d] - ebeg, n = cntl[d];
        for (int j = 0; j < n; j++){
            int s = csl[ebg + j];
            unsigned short u = f2bf(expf(lrelu(asrcl[s * 4 + hh] + adv)));
            ewl[(ebg + j) * 4 + hh] = u;
            sum += bf2f(u);
        }
        wselfl[d * 4 + hh] = wsf;
        rsuml[d * 4 + hh] = 1.f / sum;
    }
    __syncthreads();

    // phase 2: aggregate, one wave per dst node, lane = channel, b64 covers 4 heads
    float b0 = bias[lane], b1 = bias[64 + lane], b2 = bias[128 + lane], b3 = bias[192 + lane];
    for (int d = wave; d < NPG; d += 8){
        float4 ws = *(const float4*)&wselfl[d * 4];
        float4 rs = *(const float4*)&rsuml[d * 4];
        ushort4 hv = *(const ushort4*)&hl[d * 256 + lane * 4];
        float a0 = ws.x * bf2f(hv.x);
        float a1 = ws.y * bf2f(hv.y);
        float a2 = ws.z * bf2f(hv.z);
        float a3 = ws.w * bf2f(hv.w);
        int ebg = offl[d] - ebeg, n = cntl[d];
        int j = 0;
        #pragma unroll 1
        for (; j + 4 <= n; j += 4){
            #pragma unroll
            for (int k = 0; k < 4; k++){
                int s = csl[ebg + j + k];
                ushort4 w = *(const ushort4*)&ewl[(ebg + j + k) * 4];
                ushort4 x = *(const ushort4*)&hl[s * 256 + lane * 4];
                a0 = fmaf(bf2f(w.x), bf2f(x.x), a0);
                a1 = fmaf(bf2f(w.y), bf2f(x.y), a1);
                a2 = fmaf(bf2f(w.z), bf2f(x.z), a2);
                a3 = fmaf(bf2f(w.w), bf2f(x.w), a3);
            }
        }
        for (; j < n; j++){
            int s = csl[ebg + j];
            ushort4 w = *(const ushort4*)&ewl[(ebg + j) * 4];
            ushort4 x = *(const ushort4*)&hl[s * 256 + lane * 4];
            a0 = fmaf(bf2f(w.x), bf2f(x.x), a0);
            a1 = fmaf(bf2f(w.y), bf2f(x.y), a1);
            a2 = fmaf(bf2f(w.z), bf2f(x.z), a2);
            a3 = fmaf(bf2f(w.w), bf2f(x.w), a3);
        }
        size_t ob = (size_t)(base + d) * 256 + lane;
        out_bf[ob]       = f2bf(eluf(a0 * rs.x + b0));
        out_bf[ob + 64]  = f2bf(eluf(a1 * rs.y + b1));
        out_bf[ob + 128] = f2bf(eluf(a2 * rs.z + b2));
        out_bf[ob + 192] = f2bf(eluf(a3 * rs.w + b3));
    }
}

// H=1, C=64, one block (256 thr) per graph, fp32 out, no ELU (conv3 -> head).
__global__ void __launch_bounds__(256)
k_fused1(const float* __restrict__ h, const float* __restrict__ as,
         const float* __restrict__ ad, const float* __restrict__ bias,
         const int* __restrict__ csr, const int* __restrict__ noff,
         const int* __restrict__ cnt, float* __restrict__ out){
    __shared__ __align__(16) unsigned short hl[NPG * 64];  // 12800 B
    __shared__ unsigned short ewl[EW_CAP];                 // 2816 B
    __shared__ int   csl[EW_CAP];                          // 5632 B
    __shared__ float asrcl[NPG], adstl[NPG];
    __shared__ float wselfl[NPG], rsuml[NPG];
    __shared__ int offl[NPG], cntl[NPG];

    int g = blockIdx.x, t = threadIdx.x;
    int wave = t >> 6, lane = t & 63;
    int base = g * NPG;

    int ebeg = noff[base];
    int etot = noff[base + NPG - 1] + cnt[base + NPG - 1] - ebeg;
    int eln = etot < EW_CAP ? etot : EW_CAP;

    const float4* hsrc = (const float4*)(h + (size_t)base * 64);
    for (int i = t; i < NPG * 16; i += 256){
        float4 v = hsrc[i];
        ushort4 u;
        u.x = f2bf(v.x); u.y = f2bf(v.y); u.z = f2bf(v.z); u.w = f2bf(v.w);
        *(ushort4*)&hl[i * 4] = u;
    }
    for (int i = t; i < eln; i += 256) csl[i] = csr[ebeg + i] - base;
    if (t < NPG){ offl[t] = noff[base + t]; cntl[t] = cnt[base + t]; }

    float asr = as[lane], adr = ad[lane];
    for (int n = wave; n < NPG; n += 4){
        float v = h[(size_t)(base + n) * 64 + lane];
        float ps = v * asr, pd = v * adr;
        #pragma unroll
        for (int o = 32; o >= 1; o >>= 1){
            ps += __shfl_xor(ps, o);
            pd += __shfl_xor(pd, o);
        }
        if (lane == 0){ asrcl[n] = ps; adstl[n] = pd; }
    }
    __syncthreads();

    if (t < NPG){
        float adv = adstl[t];
        float wsf = expf(lrelu(asrcl[t] + adv));
        float sum = wsf;
        int ebg = offl[t] - ebeg, n = cntl[t];
        for (int j = 0; j < n; j++){
            int s = csl[ebg + j];
            unsigned short u = f2bf(expf(lrelu(asrcl[s] + adv)));
            ewl[ebg + j] = u;
            sum += bf2f(u);
        }
        wselfl[t] = wsf;
        rsuml[t] = 1.f / sum;
    }
    __syncthreads();

    float bl = bias[lane];
    for (int d = wave; d < NPG; d += 4){
        float acc = wselfl[d] * bf2f(hl[d * 64 + lane]);
        int ebg = offl[d] - ebeg, n = cntl[d];
        for (int j = 0; j < n; j++){
            int s = csl[ebg + j];
            acc = fmaf(bf2f(ewl[ebg + j]), bf2f(hl[s * 64 + lane]), acc);
        }
        out[(size_t)(base + d) * 64 + lane] = acc * rsuml[d] + bl;
    }
}

// ---------------- pooling + BN + dense head ----------------
__global__ void k_head(const float* __restrict__ x3, const float* __restrict__ gin,
                       const float* __restrict__ bn_g, const float* __restrict__ bn_b,
                       const float* __restrict__ bn_m, const float* __restrict__ bn_v,
                       const float* __restrict__ Wd1, const float* __restrict__ bd1,
                       const float* __restrict__ Wd2, const float* __restrict__ bd2,
                       const float* __restrict__ Wo, const float* __restrict__ bo,
                       float* __restrict__ out){
    __shared__ float red[256];
    __shared__ float gv[68];
    __shared__ float g2[64];
    __shared__ float g3[64];
    int g = blockIdx.x, t = threadIdx.x;
    int c = t & 63, grp = t >> 6;
    float p = 0.f;
    for (int i = grp; i < NPG; i += 4) p += x3[(g * NPG + i) * 64 + c];
    red[t] = p; __syncthreads();
    if (t < 64){
        float s = red[t] + red[t + 64] + red[t + 128] + red[t + 192];
        float mean = s * (1.f / 100.f);
        gv[t] = (mean - bn_m[t]) * rsqrtf(bn_v[t] + 1e-5f) * bn_g[t] + bn_b[t];
    } else if (t < 68){
        int j = t - 64;
        float v = gin[g * 4 + j];
        gv[t] = (v - bn_m[t]) * rsqrtf(bn_v[t] + 1e-5f) * bn_g[t] + bn_b[t];
    }
    __syncthreads();
    if (t < 64){
        float s = bd1[t];
        for (int i = 0; i < 68; i++) s += gv[i] * Wd1[i * 64 + t];
        g2[t] = seluf(s);
    }
    __syncthreads();
    if (t < 64){
        float s = bd2[t];
        for (int i = 0; i < 64; i++) s += g2[i] * Wd2[i * 64 + t];
        g3[t] = seluf(s);
    }
    __syncthreads();
    if (t == 0){
        float l0 = bo[0], l1 = bo[1];
        for (int i = 0; i < 64; i++){ l0 += g3[i] * Wo[i * 2]; l1 += g3[i] * Wo[i * 2 + 1]; }
        float mx = fmaxf(l0, l1);
        float e0 = expf(l0 - mx), e1 = expf(l1 - mx);
        float inv = 1.f / (e0 + e1);
        out[g * 2] = e0 * inv;
        out[g * 2 + 1] = e1 * inv;
    }
}

extern "C" void kernel_launch(void* const* d_in, const int* in_sizes, int n_in,
                              void* d_out, int out_size, void* d_ws, size_t ws_size,
                              hipStream_t stream){
    const float* x   = (const float*)d_in[0];
    const int*   ei  = (const int*)d_in[1];
    const float* gin = (const float*)d_in[2];
    const float* gn_w = (const float*)d_in[4];
    const float* gn_b = (const float*)d_in[5];
    const float* gn_ms = (const float*)d_in[6];
    const float* W1 = (const float*)d_in[7];
    const float* as1 = (const float*)d_in[8];
    const float* ad1 = (const float*)d_in[9];
    const float* b1 = (const float*)d_in[10];
    const float* W2 = (const float*)d_in[11];
    const float* as2 = (const float*)d_in[12];
    const float* ad2 = (const float*)d_in[13];
    const float* b2 = (const float*)d_in[14];
    const float* W3 = (const float*)d_in[15];
    const float* as3 = (const float*)d_in[16];
    const float* ad3 = (const float*)d_in[17];
    const float* b3 = (const float*)d_in[18];
    const float* bn_g = (const float*)d_in[19];
    const float* bn_b = (const float*)d_in[20];
    const float* bn_m = (const float*)d_in[21];
    const float* bn_v = (const float*)d_in[22];
    const float* Wd1 = (const float*)d_in[23];
    const float* bd1 = (const float*)d_in[24];
    const float* Wd2 = (const float*)d_in[25];
    const float* bd2 = (const float*)d_in[26];
    const float* Wo = (const float*)d_in[27];
    const float* bo = (const float*)d_in[28];
    float* out = (float*)d_out;

    const int* src = ei;
    const int* dst = ei + N_EDGES;

    char* ws = (char*)d_ws;
    size_t off = 0;
    auto alloc = [&](size_t bytes) -> void* {
        void* p = ws + off;
        off = (off + bytes + 255) & ~(size_t)255;
        return p;
    };
    int* counts     = (int*)alloc((size_t)N_NODES * 4);
    int* local_off  = (int*)alloc((size_t)N_NODES * 4);
    int* node_off   = (int*)alloc((size_t)N_NODES * 4);
    int* write_ptr  = (int*)alloc((size_t)N_NODES * 4);
    int* graph_tot  = (int*)alloc(512 * 4);
    int* graph_base = (int*)alloc(512 * 4);
    int* csr        = (int*)alloc((size_t)N_EDGES * 4);
    float* y        = (float*)alloc((size_t)N_NODES * F_IN * 4);
    unsigned short* wp2 = (unsigned short*)alloc((size_t)256 * 256 * 2);
    unsigned short* wp3 = (unsigned short*)alloc((size_t)256 * 64 * 2);
    float* bufA     = (float*)alloc((size_t)N_NODES * 256 * 4);          // h (fp32 GEMM out)
    unsigned short* xb = (unsigned short*)alloc((size_t)N_ROWS_PAD * 256 * 2); // bf16 GEMM input
    float* bufC     = (float*)alloc((size_t)N_NODES * HID * 4);          // conv3 gemm out
    float* bufD     = (float*)alloc((size_t)N_NODES * HID * 4);          // conv3 agg out

    // --- CSR build ---
    hipMemsetAsync(counts, 0, (size_t)N_NODES * 4, stream);
    k_count<<<(N_EDGES + 255) / 256, 256, 0, stream>>>(dst, counts);
    k_local_scan<<<N_GRAPHS, 128, 0, stream>>>(counts, local_off, graph_tot);
    k_graph_scan<<<1, 512, 0, stream>>>(graph_tot, graph_base);
    k_off<<<(N_NODES + 255) / 256, 256, 0, stream>>>(local_off, graph_base, node_off, write_ptr);
    k_scatter<<<(N_EDGES + 255) / 256, 256, 0, stream>>>(src, dst, write_ptr, csr);

    // --- weight packs (bf16, MFMA-B order) ---
    k_pack_w<<<(256 * 256 + 255) / 256, 256, 0, stream>>>(W2, wp2, 256, 256);
    k_pack_w<<<(256 * 64 + 255) / 256, 256, 0, stream>>>(W3, wp3, 256, 64);

    // --- GraphNorm ---
    k_gnorm<<<N_GRAPHS, 256, 0, stream>>>(x, gn_w, gn_b, gn_ms, y);

    dim3 gemm_grid4(4, (N_NODES + 63) / 64);
    dim3 mfma_grid4(4, N_ROWS_PAD / 64);
    dim3 mfma_grid1(1, N_ROWS_PAD / 64);

    // --- conv1: 16 -> 4x64, ELU ---
    k_gemm_tiled<<<gemm_grid4, 256, 0, stream>>>(y, W1, bufA, N_NODES, 16, 256);
    k_fused4<<<N_GRAPHS, 512, 0, stream>>>(bufA, as1, ad1, b1, csr, node_off, counts, xb);

    // --- conv2: 256 -> 4x64, ELU ---
    k_gemm_mfma<<<mfma_grid4, 256, 0, stream>>>(xb, wp2, bufA, N_NODES, 256, 256);
    k_fused4<<<N_GRAPHS, 512, 0, stream>>>(bufA, as2, ad2, b2, csr, node_off, counts, xb);

    // --- conv3: 256 -> 64, no ELU ---
    k_gemm_mfma<<<mfma_grid1, 256, 0, stream>>>(xb, wp3, bufC, N_NODES, 256, 64);
    k_fused1<<<N_GRAPHS, 256, 0, stream>>>(bufC, as3, ad3, b3, csr, node_off, counts, bufD);

    // --- pool + BN + dense head + softmax ---
    k_head<<<N_GRAPHS, 256, 0, stream>>>(bufD, gin, bn_g, bn_b, bn_m, bn_v,
                                         Wd1, bd1, Wd2, bd2, Wo, bo, out);
}